// Round 3
// baseline (899.405 us; speedup 1.0000x reference)
//
#include <hip/hip_runtime.h>
#include <hip/hip_bf16.h>

// Attention4DDownsample — fully fused, one workgroup per batch element.
// B=2048, 512 threads (8 waves), ~152KB LDS => 1 block/CU.
// R3: ALL global inputs/outputs are FLOAT32 (per reference setup_inputs).
//     Internals: bf16 LDS tiles + v_mfma_f32_16x16x32_bf16, fp32 accum.

#define DIMC 384
#define NPOS 49
#define NHKD 128
#define DHC  512
#define OUTC 384

typedef __attribute__((ext_vector_type(8))) __bf16 bf16x8;
typedef __attribute__((ext_vector_type(4))) float f32x4;

static __device__ __forceinline__ __hip_bfloat16 f2b(float x) { return __float2bfloat16(x); }
static __device__ __forceinline__ float b2f(__hip_bfloat16 x) { return __bfloat162float(x); }
static __device__ __forceinline__ bf16x8 ld8(const __hip_bfloat16* p) { return *(const bf16x8*)p; }
// load 8 floats -> bf16x8 fragment (RNE per-element)
static __device__ __forceinline__ bf16x8 ld8f(const float* p) {
  f32x4 a = *(const f32x4*)p;
  f32x4 b = *(const f32x4*)(p + 4);
  bf16x8 r;
  #pragma unroll
  for (int j = 0; j < 4; ++j) r[j] = (__bf16)a[j];
  #pragma unroll
  for (int j = 0; j < 4; ++j) r[4 + j] = (__bf16)b[j];
  return r;
}
static __device__ __forceinline__ f32x4 fzero() {
  f32x4 z; z[0] = 0.f; z[1] = 0.f; z[2] = 0.f; z[3] = 0.f; return z;
}
static __device__ __forceinline__ bf16x8 bzero() {
  bf16x8 z;
  #pragma unroll
  for (int j = 0; j < 8; ++j) z[j] = (__bf16)0.0f;
  return z;
}
// NaN/Inf launder: NaN -> 0, clamp +-lim. Inert for correct values; diagnostic.
static __device__ __forceinline__ float fin(float v, float lim) {
  if (__builtin_isnan(v)) return 0.f;
  return fminf(fmaxf(v, -lim), lim);
}

// y = BN(conv_out + convb):  y = conv_out * s + o     (fp32 params)
static __device__ __forceinline__ void bn_so(const float* bn, int C, int ch,
                                             float convb, float& s, float& o) {
  float g  = bn[ch];
  float be = bn[C + ch];
  float mu = bn[2*C + ch];
  float va = bn[3*C + ch];
  s = g * rsqrtf(va + 1e-5f);
  o = be + (convb - mu) * s;
}

// LDS element offsets (bf16 elems). Total 76168 elems = 152336 B.
//  xs   [49][392]  @0        (x transposed: [n][c]) — dead after GEMM1
//  attn [8][16][72]@0        (aliases xs; written in phase D)
//  rout [16][520]  @9216     (aliases xs; relu(xa+vloc) in [nq][d])
//  vsm  [512][72]  @19208    (v_out, [d][nk]; cols 49..71 zero/garbage-masked)
//  kt   [64][136]  @56072    (k_out transposed: [nk][oc])
//  qin  [16][392]  @64776    (local_q+pool, [nq][c])
//  qsm  [8][16][40]@71048    (q_out per head, [h][nq][kd], kd 16..31 zero)

__global__ __launch_bounds__(512, 2) void attn4d_kernel(
    const float* __restrict__ x,
    const float* __restrict__ qlw, const float* __restrict__ qlb,
    const float* __restrict__ qpw, const float* __restrict__ qpb,
    const float* __restrict__ qbn,
    const float* __restrict__ kw,  const float* __restrict__ kb,
    const float* __restrict__ kbn,
    const float* __restrict__ vw,  const float* __restrict__ vb,
    const float* __restrict__ vbn,
    const float* __restrict__ vlw, const float* __restrict__ vlb,
    const float* __restrict__ vlbn,
    const float* __restrict__ pw,  const float* __restrict__ pb,
    const float* __restrict__ pbn,
    const float* __restrict__ ab,  const int* __restrict__ bidx,
    int n_off, float* __restrict__ out)
{
  __shared__ __align__(16) __hip_bfloat16 smem[76168];
  __hip_bfloat16* xs    = smem;
  __hip_bfloat16* attnS = smem;
  __hip_bfloat16* rout  = smem + 9216;
  __hip_bfloat16* vsm   = smem + 19208;
  __hip_bfloat16* kt    = smem + 56072;
  __hip_bfloat16* qin   = smem + 64776;
  __hip_bfloat16* qsm   = smem + 71048;

  const int tid  = threadIdx.x;
  const int lane = tid & 63;
  const int wave = tid >> 6;     // 0..7
  const int quad = lane >> 4;    // 0..3
  const int l15  = lane & 15;
  const int b    = blockIdx.x;

  // ---------------- Phase Z: zero entire LDS (provides qsm/vsm zero padding)
  {
    unsigned int* sp = (unsigned int*)smem;          // 38084 dwords
    for (int i = tid; i < 38084; i += 512) sp[i] = 0u;
  }
  __syncthreads();

  // ---------------- Phase 0: stage x[b] (fp32) -> xs[n][c] bf16 transposed
  {
    const f32x4* xg = (const f32x4*)(x + (size_t)b * (DIMC * NPOS));
    for (int i = tid; i < (DIMC * NPOS / 4); i += 512) {   // 4704 float4s
      f32x4 v = xg[i];
      const int e0 = i * 4;
      #pragma unroll
      for (int j = 0; j < 4; ++j) {
        const int e = e0 + j;
        const int c = e / 49;
        const int n = e - c * 49;
        xs[n * 392 + c] = f2b(v[j]);
      }
    }
  }
  __syncthreads();

  // ---------------- Phase A: qin[nq][c] = local_q (dw3x3 s2 p1) + avgpool2(pad)
  if (tid < DIMC) {
    const int c = tid;
    float xv[49];
    #pragma unroll
    for (int n = 0; n < 49; ++n) xv[n] = b2f(xs[n * 392 + c]);
    float wq[9];
    #pragma unroll
    for (int j = 0; j < 9; ++j) wq[j] = qlw[c * 9 + j];
    const float cb = qlb[c];
    #pragma unroll
    for (int oh = 0; oh < 4; ++oh) {
      #pragma unroll
      for (int ow = 0; ow < 4; ++ow) {
        float a = cb;
        #pragma unroll
        for (int kh = 0; kh < 3; ++kh) {
          const int ih = 2 * oh - 1 + kh;
          if (ih < 0 || ih > 6) continue;
          #pragma unroll
          for (int kwi = 0; kwi < 3; ++kwi) {
            const int iw = 2 * ow - 1 + kwi;
            if (iw < 0 || iw > 6) continue;
            a += wq[kh * 3 + kwi] * xv[ih * 7 + iw];
          }
        }
        if (oh < 3 && ow < 3)
          a += 0.25f * (xv[(2*oh)*7 + 2*ow] + xv[(2*oh)*7 + 2*ow + 1] +
                        xv[(2*oh+1)*7 + 2*ow] + xv[(2*oh+1)*7 + 2*ow + 1]);
        qin[(oh * 4 + ow) * 392 + c] = f2b(fin(a, 60000.f));
      }
    }
  }
  __syncthreads();

  // ---------------- Phase B: GEMM1 — k_out(128ch) & v_out(512ch) = W @ x, BN
  // 40 M-tiles; each wave: 5 M-tiles x 4 N-tiles, K=384 (12 ksteps).
  {
    const int mt0 = wave * 5;
    f32x4 acc[5][4];
    #pragma unroll
    for (int t = 0; t < 5; ++t)
      #pragma unroll
      for (int nt = 0; nt < 4; ++nt) acc[t][nt] = fzero();
    for (int ks = 0; ks < 12; ++ks) {
      const int c0 = ks * 32 + quad * 8;
      bf16x8 bfr[4];
      #pragma unroll
      for (int nt = 0; nt < 4; ++nt) {
        bf16x8 z = bzero();
        const int n = nt * 16 + l15;
        if (n < 49) z = ld8(&xs[n * 392 + c0]);
        bfr[nt] = z;
      }
      #pragma unroll
      for (int t = 0; t < 5; ++t) {
        const int oc = (mt0 + t) * 16 + l15;
        const float* wp = (oc < NHKD) ? (kw + oc * DIMC) : (vw + (oc - NHKD) * DIMC);
        bf16x8 a = ld8f(wp + c0);
        #pragma unroll
        for (int nt = 0; nt < 4; ++nt)
          acc[t][nt] = __builtin_amdgcn_mfma_f32_16x16x32_bf16(a, bfr[nt], acc[t][nt], 0, 0, 0);
      }
    }
    #pragma unroll
    for (int t = 0; t < 5; ++t) {
      #pragma unroll
      for (int r = 0; r < 4; ++r) {
        const int oc = (mt0 + t) * 16 + quad * 4 + r;
        float s, o;
        if (oc < NHKD) bn_so(kbn, NHKD, oc, kb[oc], s, o);
        else           bn_so(vbn, DHC, oc - NHKD, vb[oc - NHKD], s, o);
        #pragma unroll
        for (int nt = 0; nt < 4; ++nt) {
          const int n = nt * 16 + l15;
          const float val = fin(acc[t][nt][r] * s + o, 60000.f);
          if (oc < NHKD) kt[n * 136 + oc] = f2b(val);
          else           vsm[(oc - NHKD) * 72 + n] = f2b(val);
        }
      }
    }
  }
  __syncthreads();

  // ---------------- Phase C: q GEMM — q_out = BN(qpw @ qin) -> qsm[h][nq][kd]
  {
    const int mt = wave;   // 8 M-tiles of 16 channels
    f32x4 acc = fzero();
    for (int ks = 0; ks < 12; ++ks) {
      const int c0 = ks * 32 + quad * 8;
      bf16x8 bv = ld8(&qin[l15 * 392 + c0]);
      bf16x8 av = ld8f(&qpw[(mt * 16 + l15) * DIMC + c0]);
      acc = __builtin_amdgcn_mfma_f32_16x16x32_bf16(av, bv, acc, 0, 0, 0);
    }
    #pragma unroll
    for (int r = 0; r < 4; ++r) {
      const int oc = mt * 16 + quad * 4 + r;
      float s, o;
      bn_so(qbn, NHKD, oc, qpb[oc], s, o);
      const int h = oc >> 4, kd = oc & 15;
      qsm[h * 640 + l15 * 40 + kd] = f2b(fin(acc[r] * s + o, 60000.f));
    }
  }
  __syncthreads();

  // ---------------- Phase D: QK^T*scale + bias, softmax -> attnS[h][nq][nk]
  {
    const int h = wave;
    bf16x8 av = ld8(&qsm[h * 640 + l15 * 40 + quad * 8]);   // A[nq][kd], kd>=16 zero
    float p[4][4];   // [tile][r]
    #pragma unroll
    for (int t = 0; t < 4; ++t) {
      bf16x8 bv = bzero();
      if (quad < 2) bv = ld8(&kt[(t * 16 + l15) * 136 + h * 16 + quad * 8]);
      f32x4 lg = __builtin_amdgcn_mfma_f32_16x16x32_bf16(av, bv, fzero(), 0, 0, 0);
      #pragma unroll
      for (int r = 0; r < 4; ++r) {
        const int nq = quad * 4 + r;
        const int nk = t * 16 + l15;
        float val = -30000.f;
        if (nk < 49) {
          int idx = bidx[nq * 49 + nk];
          float bias = 0.f;
          if (idx >= 0 && idx < n_off) bias = ab[h * n_off + idx];
          val = fin(lg[r] * 0.25f + bias, 30000.f);
        }
        p[t][r] = val;
      }
    }
    #pragma unroll
    for (int r = 0; r < 4; ++r) {
      float m = fmaxf(fmaxf(p[0][r], p[1][r]), fmaxf(p[2][r], p[3][r]));
      m = fmaxf(m, __shfl_xor(m, 1));
      m = fmaxf(m, __shfl_xor(m, 2));
      m = fmaxf(m, __shfl_xor(m, 4));
      m = fmaxf(m, __shfl_xor(m, 8));
      float e[4], sum = 0.f;
      #pragma unroll
      for (int t = 0; t < 4; ++t) { e[t] = __expf(p[t][r] - m); sum += e[t]; }
      sum += __shfl_xor(sum, 1);
      sum += __shfl_xor(sum, 2);
      sum += __shfl_xor(sum, 4);
      sum += __shfl_xor(sum, 8);
      const float inv = 1.f / fmaxf(sum, 1e-30f);
      #pragma unroll
      for (int t = 0; t < 4; ++t) p[t][r] = fin(e[t] * inv, 1.f);
    }
    #pragma unroll
    for (int r = 0; r < 4; ++r) {
      const int nq = quad * 4 + r;
      #pragma unroll
      for (int t = 0; t < 4; ++t)
        attnS[h * 1152 + nq * 72 + (t * 16 + l15)] = f2b(p[t][r]);
    }
  }
  __syncthreads();

  // ---------------- Phase E-a: v_local = BN(dw3x3 s2 p1 (v_out)) -> rout[nq][d]
  {
    const int d = tid;   // 0..511
    float vv[49];
    #pragma unroll
    for (int n = 0; n < 49; ++n) vv[n] = b2f(vsm[d * 72 + n]);
    float wv[9];
    #pragma unroll
    for (int j = 0; j < 9; ++j) wv[j] = vlw[d * 9 + j];
    float s, o;
    bn_so(vlbn, DHC, d, vlb[d], s, o);
    #pragma unroll
    for (int oh = 0; oh < 4; ++oh) {
      #pragma unroll
      for (int ow = 0; ow < 4; ++ow) {
        float a = 0.f;
        #pragma unroll
        for (int kh = 0; kh < 3; ++kh) {
          const int ih = 2 * oh - 1 + kh;
          if (ih < 0 || ih > 6) continue;
          #pragma unroll
          for (int kwi = 0; kwi < 3; ++kwi) {
            const int iw = 2 * ow - 1 + kwi;
            if (iw < 0 || iw > 6) continue;
            a += wv[kh * 3 + kwi] * vv[ih * 7 + iw];
          }
        }
        rout[(oh * 4 + ow) * 520 + d] = f2b(fin(a * s + o, 60000.f));
      }
    }
  }
  __syncthreads();

  // ---------------- Phase E-b: PV — xa[d][nq]; rout = relu(xa + vloc)
  {
    const int h = wave;
    f32x4 acc[4];
    #pragma unroll
    for (int mt = 0; mt < 4; ++mt) acc[mt] = fzero();
    #pragma unroll
    for (int ks = 0; ks < 2; ++ks) {
      const int k0 = ks * 32 + quad * 8;
      bf16x8 bv = ld8(&attnS[h * 1152 + l15 * 72 + k0]);          // B[nq][nk]
      #pragma unroll
      for (int mt = 0; mt < 4; ++mt) {
        bf16x8 av = ld8(&vsm[(h * 64 + mt * 16 + l15) * 72 + k0]); // A[d][nk]
        acc[mt] = __builtin_amdgcn_mfma_f32_16x16x32_bf16(av, bv, acc[mt], 0, 0, 0);
      }
    }
    #pragma unroll
    for (int mt = 0; mt < 4; ++mt) {
      #pragma unroll
      for (int r = 0; r < 4; ++r) {
        const int d = h * 64 + mt * 16 + quad * 4 + r;
        const int ad = l15 * 520 + d;
        const float val = fin(acc[mt][r] + b2f(rout[ad]), 60000.f);
        rout[ad] = f2b(fmaxf(val, 0.f));
      }
    }
  }
  __syncthreads();

  // ---------------- Phase F: proj GEMM — out = BN(pw @ rout + pb), fp32 store
  {
    const int mt0 = wave * 3;   // 24 M-tiles over 8 waves
    f32x4 acc[3];
    #pragma unroll
    for (int t = 0; t < 3; ++t) acc[t] = fzero();
    for (int ks = 0; ks < 16; ++ks) {
      const int c0 = ks * 32 + quad * 8;
      bf16x8 bv = ld8(&rout[l15 * 520 + c0]);
      #pragma unroll
      for (int t = 0; t < 3; ++t) {
        bf16x8 av = ld8f(&pw[((mt0 + t) * 16 + l15) * DHC + c0]);
        acc[t] = __builtin_amdgcn_mfma_f32_16x16x32_bf16(av, bv, acc[t], 0, 0, 0);
      }
    }
    float* outb = out + (size_t)b * (OUTC * 16);
    #pragma unroll
    for (int t = 0; t < 3; ++t) {
      #pragma unroll
      for (int r = 0; r < 4; ++r) {
        const int oc = (mt0 + t) * 16 + quad * 4 + r;
        float s, o;
        bn_so(pbn, OUTC, oc, pb[oc], s, o);
        outb[oc * 16 + l15] = fin(acc[t][r] * s + o, 60000.f);
      }
    }
  }
}

extern "C" void kernel_launch(void* const* d_in, const int* in_sizes, int n_in,
                              void* d_out, int out_size, void* d_ws, size_t ws_size,
                              hipStream_t stream) {
  const float* x    = (const float*)d_in[0];
  const float* qlw  = (const float*)d_in[1];
  const float* qlb  = (const float*)d_in[2];
  const float* qpw  = (const float*)d_in[3];
  const float* qpb  = (const float*)d_in[4];
  const float* qbn  = (const float*)d_in[5];
  const float* kw   = (const float*)d_in[6];
  const float* kb   = (const float*)d_in[7];
  const float* kbn  = (const float*)d_in[8];
  const float* vw   = (const float*)d_in[9];
  const float* vb   = (const float*)d_in[10];
  const float* vbn  = (const float*)d_in[11];
  const float* vlw  = (const float*)d_in[12];
  const float* vlb  = (const float*)d_in[13];
  const float* vlbn = (const float*)d_in[14];
  const float* pw   = (const float*)d_in[15];
  const float* pb   = (const float*)d_in[16];
  const float* pbn  = (const float*)d_in[17];
  const float* ab   = (const float*)d_in[18];
  const int*   bidx = (const int*)d_in[19];
  const int n_off = in_sizes[18] / 8;
  const int Bn = in_sizes[0] / (DIMC * NPOS);   // 2048

  attn4d_kernel<<<Bn, 512, 0, stream>>>(x, qlw, qlb, qpw, qpb, qbn, kw, kb, kbn,
                                        vw, vb, vbn, vlw, vlb, vlbn, pw, pb, pbn,
                                        ab, bidx, n_off, (float*)d_out);
}

// Round 4
// 627.993 us; speedup vs baseline: 1.4322x; 1.4322x over previous
//
#include <hip/hip_runtime.h>
#include <hip/hip_bf16.h>

// Attention4DDownsample — fused, one workgroup per batch element, v-path chunked.
// R4: (1) prep kernel converts all GEMM weights fp32->bf16 into d_ws (983 KB).
//     (2) main kernel LDS cut 152 KB -> 81,680 B => 2 blocks/CU (16 waves).
//     v processed in 8 chunks of 64 channels: vGEMM -> v_local -> PV per chunk.

#define DIMC 384
#define NPOS 49
#define NHKD 128
#define DHC  512
#define OUTC 384

// ws bf16 weight offsets (elements)
#define OFF_KW  0
#define OFF_VW  49152
#define OFF_QPW 245760
#define OFF_PW  294912
#define W_TOT   491520

// LDS regions (bf16 element offsets), total 40840 elems = 81680 B (2 blocks/CU)
#define XS_OFF 0       // xs   [49][392]  x^T [n][c]           (alive: P0..last vGEMM)
#define R0_OFF 19208   // kt   [64][136] -> rout [16][520]     (kt dead after attn)
#define R1_OFF 27528   // qsm  [8][16][40] -> vsm [64][72]     (qsm dead after attn)
#define R2_OFF 32648   // qin  [16][392] -> attnS [8][16][64]  (qin dead after qGEMM)
#define SMEM_ELEMS 40840

typedef __attribute__((ext_vector_type(8))) __bf16 bf16x8;
typedef __attribute__((ext_vector_type(4))) float f32x4;

static __device__ __forceinline__ __hip_bfloat16 f2b(float x) { return __float2bfloat16(x); }
static __device__ __forceinline__ float b2f(__hip_bfloat16 x) { return __bfloat162float(x); }
static __device__ __forceinline__ bf16x8 ld8(const __hip_bfloat16* p) { return *(const bf16x8*)p; }
static __device__ __forceinline__ f32x4 fzero() {
  f32x4 z; z[0] = 0.f; z[1] = 0.f; z[2] = 0.f; z[3] = 0.f; return z;
}
static __device__ __forceinline__ bf16x8 bzero() {
  bf16x8 z;
  #pragma unroll
  for (int j = 0; j < 8; ++j) z[j] = (__bf16)0.0f;
  return z;
}

// y = conv_out * s + o  implements BN(conv_out + convb)
static __device__ __forceinline__ void bn_so(const float* bn, int C, int ch,
                                             float convb, float& s, float& o) {
  float g  = bn[ch];
  float be = bn[C + ch];
  float mu = bn[2*C + ch];
  float va = bn[3*C + ch];
  s = g * rsqrtf(va + 1e-5f);
  o = be + (convb - mu) * s;
}

// ---------------- prep: fp32 weights -> bf16 in ws ----------------
__global__ void prep_weights(const float* __restrict__ kw, const float* __restrict__ vw,
                             const float* __restrict__ qpw, const float* __restrict__ pw,
                             __hip_bfloat16* __restrict__ wsb) {
  for (int i = blockIdx.x * blockDim.x + threadIdx.x; i < W_TOT; i += gridDim.x * blockDim.x) {
    float v;
    if (i < OFF_VW)       v = kw[i - OFF_KW];
    else if (i < OFF_QPW) v = vw[i - OFF_VW];
    else if (i < OFF_PW)  v = qpw[i - OFF_QPW];
    else                  v = pw[i - OFF_PW];
    wsb[i] = f2b(v);
  }
}

// ---------------- main fused kernel ----------------
__global__ __launch_bounds__(512, 4) void attn4d_kernel(
    const float* __restrict__ x,
    const float* __restrict__ qlw, const float* __restrict__ qlb,
    const float* __restrict__ qpb, const float* __restrict__ qbn,
    const float* __restrict__ kb,  const float* __restrict__ kbn,
    const float* __restrict__ vb,  const float* __restrict__ vbn,
    const float* __restrict__ vlw, const float* __restrict__ vlb,
    const float* __restrict__ vlbn,
    const float* __restrict__ pb,  const float* __restrict__ pbn,
    const float* __restrict__ ab,  const int* __restrict__ bidx,
    const __hip_bfloat16* __restrict__ wsb,
    int n_off, float* __restrict__ out)
{
  __shared__ __align__(16) __hip_bfloat16 smem[SMEM_ELEMS];
  __hip_bfloat16* xs    = smem + XS_OFF;
  __hip_bfloat16* kt    = smem + R0_OFF;   // [nk][oc] stride 136, rows <49 written
  __hip_bfloat16* rout  = smem + R0_OFF;   // [nq][d]  stride 520
  __hip_bfloat16* qsm   = smem + R1_OFF;   // [h][nq][kd] stride 40, kd16..31 zeroed
  __hip_bfloat16* vsm   = smem + R1_OFF;   // [64][72] per-chunk v
  __hip_bfloat16* qin   = smem + R2_OFF;   // [16][392]
  __hip_bfloat16* attnS = smem + R2_OFF;   // [h][nq][nk] stride 64

  const __hip_bfloat16* kwb  = wsb + OFF_KW;
  const __hip_bfloat16* vwb  = wsb + OFF_VW;
  const __hip_bfloat16* qpwb = wsb + OFF_QPW;
  const __hip_bfloat16* pwb  = wsb + OFF_PW;

  const int tid  = threadIdx.x;
  const int lane = tid & 63;
  const int wave = tid >> 6;     // 0..7
  const int quad = lane >> 4;    // 0..3
  const int l15  = lane & 15;
  const int b    = blockIdx.x;

  // ---- P0: stage x[b] (fp32 global) -> xs[n][c] bf16 transposed
  {
    const f32x4* xg = (const f32x4*)(x + (size_t)b * (DIMC * NPOS));
    for (int i = tid; i < (DIMC * NPOS / 4); i += 512) {   // 4704 float4s
      f32x4 v = xg[i];
      const int e0 = i * 4;
      #pragma unroll
      for (int j = 0; j < 4; ++j) {
        const int e = e0 + j;
        const int c = e / 49;
        const int n = e - c * 49;
        xs[n * 392 + c] = f2b(v[j]);
      }
    }
  }
  __syncthreads();

  // ---- PA: qin[nq][c] = dw3x3 s2 p1 (local_q) + avgpool2 (zero-padded)
  if (tid < DIMC) {
    const int c = tid;
    float xv[49];
    #pragma unroll
    for (int n = 0; n < 49; ++n) xv[n] = b2f(xs[n * 392 + c]);
    float wq[9];
    #pragma unroll
    for (int j = 0; j < 9; ++j) wq[j] = qlw[c * 9 + j];
    const float cb = qlb[c];
    #pragma unroll
    for (int oh = 0; oh < 4; ++oh) {
      #pragma unroll
      for (int ow = 0; ow < 4; ++ow) {
        float a = cb;
        #pragma unroll
        for (int kh = 0; kh < 3; ++kh) {
          const int ih = 2 * oh - 1 + kh;
          if (ih < 0 || ih > 6) continue;
          #pragma unroll
          for (int kwi = 0; kwi < 3; ++kwi) {
            const int iw = 2 * ow - 1 + kwi;
            if (iw < 0 || iw > 6) continue;
            a += wq[kh * 3 + kwi] * xv[ih * 7 + iw];
          }
        }
        if (oh < 3 && ow < 3)
          a += 0.25f * (xv[(2*oh)*7 + 2*ow] + xv[(2*oh)*7 + 2*ow + 1] +
                        xv[(2*oh+1)*7 + 2*ow] + xv[(2*oh+1)*7 + 2*ow + 1]);
        qin[(oh * 4 + ow) * 392 + c] = f2b(a);
      }
    }
  }
  __syncthreads();

  // ---- PBk: k GEMM (128 ch): wave = M-tile, 4 N-tiles, K=384
  {
    const int mt = wave;
    f32x4 acc[4];
    #pragma unroll
    for (int nt = 0; nt < 4; ++nt) acc[nt] = fzero();
    for (int ks = 0; ks < 12; ++ks) {
      const int c0 = ks * 32 + quad * 8;
      bf16x8 a = ld8(&kwb[(mt * 16 + l15) * DIMC + c0]);
      #pragma unroll
      for (int nt = 0; nt < 4; ++nt) {
        bf16x8 z = bzero();
        const int n = nt * 16 + l15;
        if (n < 49) z = ld8(&xs[n * 392 + c0]);
        acc[nt] = __builtin_amdgcn_mfma_f32_16x16x32_bf16(a, z, acc[nt], 0, 0, 0);
      }
    }
    #pragma unroll
    for (int r = 0; r < 4; ++r) {
      const int oc = mt * 16 + quad * 4 + r;
      float s, o;
      bn_so(kbn, NHKD, oc, kb[oc], s, o);
      #pragma unroll
      for (int nt = 0; nt < 4; ++nt) {
        const int n = nt * 16 + l15;
        if (n < 49) kt[n * 136 + oc] = f2b(acc[nt][r] * s + o);
        // rows 49..63 left stale: only feed discarded nk>=49 logit columns
      }
    }
  }
  __syncthreads();

  // ---- PC: q GEMM -> qsm[h][nq][kd], zero kd 16..31 pad (A-frag pad!)
  {
    const int mt = wave;
    f32x4 acc = fzero();
    for (int ks = 0; ks < 12; ++ks) {
      const int c0 = ks * 32 + quad * 8;
      bf16x8 bv = ld8(&qin[l15 * 392 + c0]);
      bf16x8 av = ld8(&qpwb[(mt * 16 + l15) * DIMC + c0]);
      acc = __builtin_amdgcn_mfma_f32_16x16x32_bf16(av, bv, acc, 0, 0, 0);
    }
    #pragma unroll
    for (int r = 0; r < 4; ++r) {
      const int oc = mt * 16 + quad * 4 + r;
      float s, o;
      bn_so(qbn, NHKD, oc, qpb[oc], s, o);
      const int kd = oc & 15;
      qsm[wave * 640 + l15 * 40 + kd] = f2b(acc[r] * s + o);
      qsm[wave * 640 + l15 * 40 + kd + 16] = f2b(0.f);
    }
  }
  __syncthreads();

  // ---- PD: QK^T*scale + bias, softmax -> attnS[h][nq][nk] (stride 64)
  {
    const int h = wave;
    bf16x8 av = ld8(&qsm[h * 640 + l15 * 40 + quad * 8]);
    float p[4][4];
    #pragma unroll
    for (int t = 0; t < 4; ++t) {
      bf16x8 bv = bzero();
      if (quad < 2) bv = ld8(&kt[(t * 16 + l15) * 136 + h * 16 + quad * 8]);
      f32x4 lg = __builtin_amdgcn_mfma_f32_16x16x32_bf16(av, bv, fzero(), 0, 0, 0);
      #pragma unroll
      for (int r = 0; r < 4; ++r) {
        const int nq = quad * 4 + r;
        const int nk = t * 16 + l15;
        float val = -30000.f;
        if (nk < 49) val = lg[r] * 0.25f + ab[h * n_off + bidx[nq * 49 + nk]];
        p[t][r] = val;
      }
    }
    #pragma unroll
    for (int r = 0; r < 4; ++r) {
      float m = fmaxf(fmaxf(p[0][r], p[1][r]), fmaxf(p[2][r], p[3][r]));
      m = fmaxf(m, __shfl_xor(m, 1));
      m = fmaxf(m, __shfl_xor(m, 2));
      m = fmaxf(m, __shfl_xor(m, 4));
      m = fmaxf(m, __shfl_xor(m, 8));
      float e[4], sum = 0.f;
      #pragma unroll
      for (int t = 0; t < 4; ++t) { e[t] = __expf(p[t][r] - m); sum += e[t]; }
      sum += __shfl_xor(sum, 1);
      sum += __shfl_xor(sum, 2);
      sum += __shfl_xor(sum, 4);
      sum += __shfl_xor(sum, 8);
      const float inv = 1.f / sum;
      #pragma unroll
      for (int t = 0; t < 4; ++t) p[t][r] = e[t] * inv;   // exactly 0 for nk>=49
    }
    #pragma unroll
    for (int r = 0; r < 4; ++r) {
      const int nq = quad * 4 + r;
      #pragma unroll
      for (int t = 0; t < 4; ++t)
        attnS[h * 1024 + nq * 64 + (t * 16 + l15)] = f2b(p[t][r]);
    }
  }
  __syncthreads();

  // ---- 8 chunks of 64 v-channels (= 1 head each): vGEMM -> v_local -> PV
  for (int c = 0; c < 8; ++c) {
    // vGEMM: 4 M-tiles x 4 N-tiles = 16 jobs over 8 waves (2 each)
    {
      const int mt = wave >> 1;
      const int bnt = (wave & 1) * 2;
      f32x4 acc[2];
      acc[0] = fzero(); acc[1] = fzero();
      for (int ks = 0; ks < 12; ++ks) {
        const int c0 = ks * 32 + quad * 8;
        bf16x8 a = ld8(&vwb[(c * 64 + mt * 16 + l15) * DIMC + c0]);
        #pragma unroll
        for (int i = 0; i < 2; ++i) {
          bf16x8 z = bzero();
          const int n = (bnt + i) * 16 + l15;
          if (n < 49) z = ld8(&xs[n * 392 + c0]);
          acc[i] = __builtin_amdgcn_mfma_f32_16x16x32_bf16(a, z, acc[i], 0, 0, 0);
        }
      }
      #pragma unroll
      for (int r = 0; r < 4; ++r) {
        const int ocl = mt * 16 + quad * 4 + r;
        float s, o;
        bn_so(vbn, DHC, c * 64 + ocl, vb[c * 64 + ocl], s, o);
        #pragma unroll
        for (int i = 0; i < 2; ++i) {
          const int n = (bnt + i) * 16 + l15;
          // write ALL n (n>=49 gets finite o) — PV multiplies those by attn==0
          vsm[ocl * 72 + n] = f2b(acc[i][r] * s + o);
        }
      }
    }
    __syncthreads();

    // v_local: wave w handles output positions {2w, 2w+1}; lane = channel d
    {
      const int d = lane;          // 0..63
      const int ch = c * 64 + d;
      float wv[9];
      #pragma unroll
      for (int j = 0; j < 9; ++j) wv[j] = vlw[ch * 9 + j];
      float s, o;
      bn_so(vlbn, DHC, ch, vlb[ch], s, o);
      #pragma unroll
      for (int pi = 0; pi < 2; ++pi) {
        const int pos = wave * 2 + pi;
        const int oh = pos >> 2, ow = pos & 3;
        float a = 0.f;
        #pragma unroll
        for (int kh = 0; kh < 3; ++kh) {
          const int ih = 2 * oh - 1 + kh;
          if (ih < 0 || ih > 6) continue;
          #pragma unroll
          for (int kwi = 0; kwi < 3; ++kwi) {
            const int iw = 2 * ow - 1 + kwi;
            if (iw < 0 || iw > 6) continue;
            a += wv[kh * 3 + kwi] * b2f(vsm[d * 72 + ih * 7 + iw]);
          }
        }
        rout[pos * 520 + c * 64 + d] = f2b(a * s + o);
      }
    }
    __syncthreads();

    // PV (head h = c): 4 M-tiles over waves 0..3; rout = relu(xa + vloc)
    if (wave < 4) {
      const int mt = wave;
      f32x4 acc = fzero();
      #pragma unroll
      for (int ks = 0; ks < 2; ++ks) {
        const int k0 = ks * 32 + quad * 8;
        bf16x8 av = ld8(&vsm[(mt * 16 + l15) * 72 + k0]);        // A[d][nk]
        bf16x8 bv = ld8(&attnS[c * 1024 + l15 * 64 + k0]);       // B[nq][nk]
        acc = __builtin_amdgcn_mfma_f32_16x16x32_bf16(av, bv, acc, 0, 0, 0);
      }
      #pragma unroll
      for (int r = 0; r < 4; ++r) {
        const int ad = l15 * 520 + c * 64 + mt * 16 + quad * 4 + r;
        const float val = acc[r] + b2f(rout[ad]);
        rout[ad] = f2b(fmaxf(val, 0.f));
      }
    }
    __syncthreads();
  }

  // ---- PF: proj GEMM — out = BN(pw @ rout + pb), fp32 store
  {
    const int mt0 = wave * 3;
    f32x4 acc[3];
    #pragma unroll
    for (int t = 0; t < 3; ++t) acc[t] = fzero();
    for (int ks = 0; ks < 16; ++ks) {
      const int c0 = ks * 32 + quad * 8;
      bf16x8 bv = ld8(&rout[l15 * 520 + c0]);
      #pragma unroll
      for (int t = 0; t < 3; ++t) {
        bf16x8 av = ld8(&pwb[((mt0 + t) * 16 + l15) * DHC + c0]);
        acc[t] = __builtin_amdgcn_mfma_f32_16x16x32_bf16(av, bv, acc[t], 0, 0, 0);
      }
    }
    float* outb = out + (size_t)b * (OUTC * 16);
    #pragma unroll
    for (int t = 0; t < 3; ++t) {
      #pragma unroll
      for (int r = 0; r < 4; ++r) {
        const int oc = (mt0 + t) * 16 + quad * 4 + r;
        float s, o;
        bn_so(pbn, OUTC, oc, pb[oc], s, o);
        outb[oc * 16 + l15] = acc[t][r] * s + o;
      }
    }
  }
}

extern "C" void kernel_launch(void* const* d_in, const int* in_sizes, int n_in,
                              void* d_out, int out_size, void* d_ws, size_t ws_size,
                              hipStream_t stream) {
  const float* x    = (const float*)d_in[0];
  const float* qlw  = (const float*)d_in[1];
  const float* qlb  = (const float*)d_in[2];
  const float* qpw  = (const float*)d_in[3];
  const float* qpb  = (const float*)d_in[4];
  const float* qbn  = (const float*)d_in[5];
  const float* kw   = (const float*)d_in[6];
  const float* kb   = (const float*)d_in[7];
  const float* kbn  = (const float*)d_in[8];
  const float* vw   = (const float*)d_in[9];
  const float* vb   = (const float*)d_in[10];
  const float* vbn  = (const float*)d_in[11];
  const float* vlw  = (const float*)d_in[12];
  const float* vlb  = (const float*)d_in[13];
  const float* vlbn = (const float*)d_in[14];
  const float* pw   = (const float*)d_in[15];
  const float* pb   = (const float*)d_in[16];
  const float* pbn  = (const float*)d_in[17];
  const float* ab   = (const float*)d_in[18];
  const int*   bidx = (const int*)d_in[19];
  const int n_off = in_sizes[18] / 8;
  const int Bn = in_sizes[0] / (DIMC * NPOS);   // 2048

  __hip_bfloat16* wsb = (__hip_bfloat16*)d_ws;  // 983,040 B used

  prep_weights<<<480, 256, 0, stream>>>(kw, vw, qpw, pw, wsb);
  attn4d_kernel<<<Bn, 512, 0, stream>>>(x, qlw, qlb, qpb, qbn, kb, kbn,
                                        vb, vbn, vlw, vlb, vlbn, pb, pbn,
                                        ab, bidx, wsb, n_off, (float*)d_out);
}